// Round 1
// baseline (414.688 us; speedup 1.0000x reference)
//
#include <hip/hip_runtime.h>

// Trilinear interpolation of 2M points into a 128x128x128x16 fp32 grid.
// Layout: values[x][y][z][c], C=16 -> 64 B per voxel = 4 x float4.
// 4 lanes per point; lane handles channels [4*c4, 4*c4+4) via float4.

#define DD 128
#define HH 128
#define WW 128

__device__ __forceinline__ float4 lerp4(float4 a, float4 b, float t) {
    return make_float4(fmaf(b.x - a.x, t, a.x),
                       fmaf(b.y - a.y, t, a.y),
                       fmaf(b.z - a.z, t, a.z),
                       fmaf(b.w - a.w, t, a.w));
}

__global__ __launch_bounds__(256) void trilerp_kernel(
    const float* __restrict__ points,
    const float4* __restrict__ values,
    float4* __restrict__ out,
    int n_points)
{
    int t = blockIdx.x * blockDim.x + threadIdx.x;
    int p = t >> 2;        // point index
    int c4 = t & 3;        // which float4 of the 16 channels
    if (p >= n_points) return;

    float x = points[p * 3 + 0] * 20.0f;   // 1/VOXEL_SIZE = 20
    float y = points[p * 3 + 1] * 20.0f;
    float z = points[p * 3 + 2] * 20.0f;

    float fx = floorf(x), fy = floorf(y), fz = floorf(z);
    int x0 = min(max((int)fx, 0), DD - 1);
    int y0 = min(max((int)fy, 0), HH - 1);
    int z0 = min(max((int)fz, 0), WW - 1);
    int x1 = min(x0 + 1, DD - 1);
    int y1 = min(y0 + 1, HH - 1);
    int z1 = min(z0 + 1, WW - 1);

    float xd = x - (float)x0;
    float yd = y - (float)y0;
    float zd = z - (float)z0;

    // float4 index: (((xi*128 + yi)*128 + zi) * 4) + c4
    #define VIDX(xi, yi, zi) (((((xi) << 7) + (yi)) << 7) + (zi)) * 4 + c4

    float4 c000 = values[VIDX(x0, y0, z0)];
    float4 c001 = values[VIDX(x0, y0, z1)];
    float4 c010 = values[VIDX(x0, y1, z0)];
    float4 c011 = values[VIDX(x0, y1, z1)];
    float4 c100 = values[VIDX(x1, y0, z0)];
    float4 c101 = values[VIDX(x1, y0, z1)];
    float4 c110 = values[VIDX(x1, y1, z0)];
    float4 c111 = values[VIDX(x1, y1, z1)];
    #undef VIDX

    float4 c00 = lerp4(c000, c100, xd);
    float4 c01 = lerp4(c001, c101, xd);
    float4 c10 = lerp4(c010, c110, xd);
    float4 c11 = lerp4(c011, c111, xd);

    float4 c0 = lerp4(c00, c10, yd);
    float4 c1 = lerp4(c01, c11, yd);

    out[t] = lerp4(c0, c1, zd);
}

extern "C" void kernel_launch(void* const* d_in, const int* in_sizes, int n_in,
                              void* d_out, int out_size, void* d_ws, size_t ws_size,
                              hipStream_t stream) {
    const float* points = (const float*)d_in[0];
    const float4* values = (const float4*)d_in[1];
    float4* out = (float4*)d_out;

    int n_points = in_sizes[0] / 3;
    int total_threads = n_points * 4;
    int blocks = (total_threads + 255) / 256;

    trilerp_kernel<<<blocks, 256, 0, stream>>>(points, values, out, n_points);
}